// Round 3
// baseline (1026.582 us; speedup 1.0000x reference)
//
#include <hip/hip_runtime.h>
#include <math.h>

// Problem constants
constexpr int Bn  = 32;
constexpr int HWn = 56;
constexpr int En  = 192;
constexpr int NHn = 6;
constexpr int SH  = 3;     // shift
constexpr int HDn = 32;    // head dim
constexpr int NWn = 8;     // windows per side
constexpr int Ln  = HWn * HWn;   // 3136
constexpr int Mn  = 49;          // tokens per window
#define NEGV (-1e9f)

// ---------------------------------------------------------------------------
// Kernel A: fused QKV projection + shifted-window attention, per (window,head)
// grid = B * 8 * 8 * 6 = 12288 blocks, 256 threads
// ---------------------------------------------------------------------------
__global__ __launch_bounds__(256) void swin_qkv_attn(
    const float* __restrict__ x, const float* __restrict__ w_qkv,
    const float* __restrict__ b_qkv, const float* __restrict__ rel_bias,
    float* __restrict__ attn_buf)
{
    __shared__ float Xs[Mn][196];   // 49x192 window of x, padded stride
    __shared__ float Qs[Mn][36];
    __shared__ float Ks[Mn][36];
    __shared__ float Vs[Mn][36];
    __shared__ float Ss[Mn][49];

    const int tid = threadIdx.x;
    int blk = blockIdx.x;
    const int h  = blk % NHn; blk /= NHn;
    const int wx = blk % NWn; blk /= NWn;
    const int wy = blk % NWn; blk /= NWn;
    const int b  = blk;

    // ---- load window of X (rolled by -SHIFT => orig = shifted + SHIFT mod 56)
    for (int t = tid; t < Mn * 48; t += 256) {
        int m = t / 48, q = t % 48;
        int r = m / 7, c = m % 7;
        int oi = (wy * 7 + r + SH) % HWn;
        int oj = (wx * 7 + c + SH) % HWn;
        const float4* src = (const float4*)(x + ((size_t)((b * HWn + oi) * HWn + oj)) * En);
        *((float4*)&Xs[m][q * 4]) = src[q];
    }
    __syncthreads();

    // ---- QKV projection for this head.
    // qkv column for (channel c, component k) = c*3 + k  (K fastest per reference)
    const int tm = tid >> 5;   // 0..7  (token groups)
    const int tc = tid & 31;   // 0..31 (head-dim)
    const int colq = (h * HDn + tc) * 3;
    float acc[7][3];
    {
        float b0 = b_qkv[colq], b1 = b_qkv[colq + 1], b2 = b_qkv[colq + 2];
        #pragma unroll
        for (int i = 0; i < 7; i++) { acc[i][0] = b0; acc[i][1] = b1; acc[i][2] = b2; }
    }
    const float* wp = w_qkv + colq;
    for (int kk = 0; kk < En; kk += 4) {
        float4 xr[7];
        #pragma unroll
        for (int i = 0; i < 7; i++) {
            int m = tm + 8 * i; if (m >= Mn) m = Mn - 1;  // safe dup, store is guarded
            xr[i] = *((const float4*)&Xs[m][kk]);
        }
        float wv[4][3];
        #pragma unroll
        for (int q = 0; q < 4; q++) {
            const float* w0 = wp + (size_t)(kk + q) * 576;
            wv[q][0] = w0[0]; wv[q][1] = w0[1]; wv[q][2] = w0[2];
        }
        #pragma unroll
        for (int i = 0; i < 7; i++) {
            const float xv[4] = {xr[i].x, xr[i].y, xr[i].z, xr[i].w};
            #pragma unroll
            for (int q = 0; q < 4; q++) {
                acc[i][0] += xv[q] * wv[q][0];
                acc[i][1] += xv[q] * wv[q][1];
                acc[i][2] += xv[q] * wv[q][2];
            }
        }
    }
    const float scale = 0.17677669529663687f;  // 1/sqrt(32)
    #pragma unroll
    for (int i = 0; i < 7; i++) {
        int m = tm + 8 * i;
        if (m < Mn) {
            Qs[m][tc] = acc[i][0] * scale;
            Ks[m][tc] = acc[i][1];
            Vs[m][tc] = acc[i][2];
        }
    }
    __syncthreads();

    // ---- scores = Q K^T (+bias, +shift masks on last window row/col)
    const bool lastRow = (wy == NWn - 1);
    const bool lastCol = (wx == NWn - 1);
    for (int idx = tid; idx < Mn * Mn; idx += 256) {
        int m = idx / 49, n = idx - m * 49;
        float a = rel_bias[idx];
        if (lastRow && ((m >= 28) != (n >= 28))) a += NEGV;
        if (lastCol && ((m % 7 >= 4) != (n % 7 >= 4))) a += NEGV;
        float s = 0.f;
        #pragma unroll
        for (int d = 0; d < HDn; d += 4) {
            float4 qv = *((const float4*)&Qs[m][d]);
            float4 kv = *((const float4*)&Ks[n][d]);
            s += qv.x * kv.x + qv.y * kv.y + qv.z * kv.z + qv.w * kv.w;
        }
        Ss[m][n] = a + s;
    }
    __syncthreads();

    // ---- softmax per row: 4 lanes per row
    {
        const int g = tid >> 2, l4 = tid & 3;
        if (g < Mn) {
            float mx = -3.4e38f;
            for (int n = l4; n < Mn; n += 4) mx = fmaxf(mx, Ss[g][n]);
            mx = fmaxf(mx, __shfl_xor(mx, 1));
            mx = fmaxf(mx, __shfl_xor(mx, 2));
            float sum = 0.f;
            for (int n = l4; n < Mn; n += 4) {
                float e = __expf(Ss[g][n] - mx);
                Ss[g][n] = e;
                sum += e;
            }
            sum += __shfl_xor(sum, 1);
            sum += __shfl_xor(sum, 2);
            float inv = 1.f / sum;
            for (int n = l4; n < Mn; n += 4) Ss[g][n] *= inv;
        }
    }
    __syncthreads();

    // ---- out = P V, scatter back to un-shifted token layout
    for (int idx = tid; idx < Mn * HDn; idx += 256) {
        int m = idx >> 5, d = idx & 31;
        float a = 0.f;
        #pragma unroll 7
        for (int n = 0; n < Mn; n++) a += Ss[m][n] * Vs[n][d];
        int r = m / 7, c = m % 7;
        int oi = (wy * 7 + r + SH) % HWn;
        int oj = (wx * 7 + c + SH) % HWn;
        attn_buf[((size_t)((b * HWn + oi) * HWn + oj)) * En + h * HDn + d] = a;
    }
}

// ---------------------------------------------------------------------------
// Kernel B: output projection GEMM [100352,192] @ [192,192] + bias
// May run in-place (src == dst): tile staged in LDS before any store.
// grid = 100352/64 = 1568 blocks, 256 threads
// ---------------------------------------------------------------------------
__global__ __launch_bounds__(256) void swin_proj(
    const float* attn_buf, const float* __restrict__ w_out,
    const float* __restrict__ b_out, float* out)
{
    __shared__ float Ts[64][196];
    const int tid = threadIdx.x;
    const size_t tok0 = (size_t)blockIdx.x * 64;

    for (int t = tid; t < 64 * 48; t += 256) {
        int m = t / 48, q = t % 48;
        const float4* src = (const float4*)(attn_buf + (tok0 + m) * En);
        *((float4*)&Ts[m][q * 4]) = src[q];
    }
    __syncthreads();

    const int tm = tid >> 5, tc = tid & 31;
    float acc[8][6];
    #pragma unroll
    for (int j = 0; j < 6; j++) {
        float bj = b_out[tc + 32 * j];
        #pragma unroll
        for (int i = 0; i < 8; i++) acc[i][j] = bj;
    }
    for (int kk = 0; kk < En; kk += 4) {
        float4 xr[8];
        #pragma unroll
        for (int i = 0; i < 8; i++) xr[i] = *((const float4*)&Ts[tm + 8 * i][kk]);
        float wv[4][6];
        #pragma unroll
        for (int q = 0; q < 4; q++) {
            const float* w0 = w_out + (size_t)(kk + q) * En + tc;
            #pragma unroll
            for (int j = 0; j < 6; j++) wv[q][j] = w0[32 * j];
        }
        #pragma unroll
        for (int i = 0; i < 8; i++) {
            const float xv[4] = {xr[i].x, xr[i].y, xr[i].z, xr[i].w};
            #pragma unroll
            for (int q = 0; q < 4; q++)
                #pragma unroll
                for (int j = 0; j < 6; j++)
                    acc[i][j] += xv[q] * wv[q][j];
        }
    }
    #pragma unroll
    for (int i = 0; i < 8; i++) {
        float* dst = out + (tok0 + tm + 8 * i) * En + tc;
        #pragma unroll
        for (int j = 0; j < 6; j++) dst[32 * j] = acc[i][j];
    }
}

extern "C" void kernel_launch(void* const* d_in, const int* in_sizes, int n_in,
                              void* d_out, int out_size, void* d_ws, size_t ws_size,
                              hipStream_t stream) {
    const float* x        = (const float*)d_in[0];
    const float* w_qkv    = (const float*)d_in[1];
    const float* b_qkv    = (const float*)d_in[2];
    const float* w_out    = (const float*)d_in[3];
    const float* b_out    = (const float*)d_in[4];
    const float* rel_bias = (const float*)d_in[5];
    float* out = (float*)d_out;

    // attn staging buffer: 100352*192 floats = ~77 MB. Use d_ws if it fits,
    // else stage in d_out (kernel B is in-place-safe: LDS tile before store).
    const size_t need = (size_t)Bn * Ln * En * sizeof(float);
    float* attn_buf = (ws_size >= need) ? (float*)d_ws : out;

    swin_qkv_attn<<<Bn * NWn * NWn * NHn, 256, 0, stream>>>(x, w_qkv, b_qkv, rel_bias, attn_buf);
    swin_proj<<<(Bn * Ln) / 64, 256, 0, stream>>>(attn_buf, w_out, b_out, out);
}

// Round 5
// 354.630 us; speedup vs baseline: 2.8948x; 2.8948x over previous
//
#include <hip/hip_runtime.h>
#include <math.h>

typedef __bf16 bf16x8 __attribute__((ext_vector_type(8)));
typedef float f32x4 __attribute__((ext_vector_type(4)));
typedef unsigned short u16;

constexpr int Bn  = 32;
constexpr int HWn = 56;
constexpr int En  = 192;
constexpr int SH  = 3;
constexpr int NWn = 8;
constexpr int Ln  = HWn * HWn;
constexpr int Mn  = 49;
#define NEGV (-1e9f)

#define MFMA(a, b, c) __builtin_amdgcn_mfma_f32_16x16x32_bf16((a), (b), (c), 0, 0, 0)

__device__ __forceinline__ u16 f2b(float f) {
    unsigned u = __float_as_uint(f);
    return (u16)((u + 0x7fffu + ((u >> 16) & 1u)) >> 16);
}

// ---------------------------------------------------------------------------
// Prep: W_qkv [192][576] fp32 -> ws as bf16 [c'][k] with c' = comp*192 + e
// (de-interleaves the (channel,comp) column order; source col = e*3+comp)
// ---------------------------------------------------------------------------
__global__ __launch_bounds__(256) void prep_wt(const float* __restrict__ w,
                                               u16* __restrict__ wt) {
    int i = blockIdx.x * 256 + threadIdx.x;
    if (i >= 576 * 192) return;
    int cp = i / 192, k = i - cp * 192;
    int comp = cp / 192, e = cp - comp * 192;
    wt[i] = f2b(w[k * 576 + e * 3 + comp]);
}

// ---------------------------------------------------------------------------
// Kernel A (MFMA): fused QKV projection + shifted-window attention.
// One block per window: grid 2048, 512 threads (8 waves).
// LDS layout (bytes):
//   phase1: XS [64 rows][384B] @0 (24576) | WT [576 rows][80B padded] @24576 (46080, ends 70656)
//   phase2: QS [6][64][64B] @0 | KS @24576 | VT [6][32][128B] @49152 (ends 73728)
//   phase2b: PL [8 waves][16][128B] @0 (overlays QS after Q->regs)
// Swizzles: XS byte^(((m&3)<<4)|(((m>>2)&1)<<6)); WT: none (stride-80 pad);
//   QS/KS byte^(((row>>1)&3)<<4)  [row stride 64B: bank half = row&1, spread by row>>1];
//   VT/PL byte^(((row&7))<<4).
// kf2 (PV K-tiles) = 2: keys padded to 64 = 2 x K32 MFMAs.  (R4 NaN bug: was 4)
// ---------------------------------------------------------------------------
template<bool USE_WT>
__global__ __launch_bounds__(512, 2) void swin_attn_mfma(
    const float* __restrict__ x, const u16* __restrict__ wt,
    const float* __restrict__ wq_f32, const float* __restrict__ b_qkv,
    const float* __restrict__ rel_bias, float* __restrict__ attn_buf)
{
    __shared__ char lds[73728] __attribute__((aligned(128)));

    const int tid  = threadIdx.x;
    const int w    = tid >> 6;
    const int lane = tid & 63;
    const int lq   = lane & 15;
    const int g    = lane >> 4;

    const int blk = blockIdx.x;
    const int wx = blk & 7, wy = (blk >> 3) & 7, b = blk >> 6;

    // ---- phase 0: X window -> XS (bf16, swizzled); pad rows 49..63 zeroed
    for (int j = tid; j < 64 * 48; j += 512) {
        int m = j / 48, q = j - 48 * m;
        u16 v[4];
        if (m < Mn) {
            int rr = m / 7, cc = m - 7 * rr;
            int oi = (wy * 7 + rr + SH) % HWn;
            int oj = (wx * 7 + cc + SH) % HWn;
            const float4 f = *(const float4*)(x + ((size_t)((b * HWn + oi) * HWn + oj)) * En + 4 * q);
            v[0] = f2b(f.x); v[1] = f2b(f.y); v[2] = f2b(f.z); v[3] = f2b(f.w);
        } else { v[0] = v[1] = v[2] = v[3] = 0; }
        int xm = ((m & 3) << 4) | (((m >> 2) & 1) << 6);
        *(ushort4*)(lds + m * 384 + ((8 * q) ^ xm)) = *(ushort4*)v;
    }

    // ---- phase 1: QKV = X @ W  (M=64, N=576, K=192; 6 k-tiles of 32)
    f32x4 acc[4][5];
    const f32x4 zero4 = {0.f, 0.f, 0.f, 0.f};
    #pragma unroll
    for (int mf = 0; mf < 4; mf++)
        #pragma unroll
        for (int j = 0; j < 5; j++) acc[mf][j] = zero4;

    bf16x8 wreg[5];
    auto stage = [&](int kt) {
        #pragma unroll
        for (int i2 = 0; i2 < 5; i2++) {
            int jj = tid + 512 * i2;
            if (jj < 2304) {
                int c = jj >> 2, q = jj & 3;
                if (USE_WT) {
                    wreg[i2] = *(const bf16x8*)(wt + c * 192 + kt * 32 + q * 8);
                } else {
                    int comp = c / 192, e = c - comp * 192;
                    int col = e * 3 + comp;
                    union { bf16x8 v; u16 a[8]; } t;
                    #pragma unroll
                    for (int p = 0; p < 8; p++)
                        t.a[p] = f2b(wq_f32[(size_t)(kt * 32 + q * 8 + p) * 576 + col]);
                    wreg[i2] = t.v;
                }
            }
        }
    };

    stage(0);
    __syncthreads();                       // XS ready
    for (int kt = 0; kt < 6; kt++) {
        #pragma unroll
        for (int i2 = 0; i2 < 5; i2++) {   // regs -> WT tile (stride-80 rows)
            int jj = tid + 512 * i2;
            if (jj < 2304) {
                int c = jj >> 2, q = jj & 3;
                *(bf16x8*)(lds + 24576 + c * 80 + 16 * q) = wreg[i2];
            }
        }
        __syncthreads();                   // WT tile ready
        if (kt < 5) stage(kt + 1);         // prefetch next (hides under MFMA)

        bf16x8 af[4];
        #pragma unroll
        for (int mf = 0; mf < 4; mf++) {
            int m = 16 * mf + lq;
            int xm = ((m & 3) << 4) | (((m >> 2) & 1) << 6);
            af[mf] = *(const bf16x8*)(lds + m * 384 + ((64 * kt + 16 * g) ^ xm));
        }
        #pragma unroll
        for (int j = 0; j < 5; j++) {
            int nf = w + 8 * j;
            if (nf < 36) {
                int c = 16 * nf + lq;
                bf16x8 bfr = *(const bf16x8*)(lds + 24576 + c * 80 + 16 * g);
                #pragma unroll
                for (int mf = 0; mf < 4; mf++)
                    acc[mf][j] = MFMA(af[mf], bfr, acc[mf][j]);
            }
        }
        __syncthreads();                   // done reading WT before next write
    }

    // ---- scatter C frags (+bias, Q scale) -> QS/KS/VT (bf16, swizzled)
    const float qscale = 0.17677669529663687f;  // 1/sqrt(32)
    #pragma unroll
    for (int j = 0; j < 5; j++) {
        int nf = w + 8 * j;
        if (nf >= 36) continue;
        int comp = nf / 12;
        int e = (nf - comp * 12) * 16 + lq;
        float bcol = b_qkv[e * 3 + comp];
        int h = e >> 5, d = e & 31;
        #pragma unroll
        for (int mf = 0; mf < 4; mf++) {
            #pragma unroll
            for (int r = 0; r < 4; r++) {
                int m = 16 * mf + 4 * g + r;
                float v = acc[mf][j][r] + bcol;
                int byte;
                if (comp == 0) { v *= qscale; byte = h * 4096 + m * 64 + ((2 * d) ^ (((m >> 1) & 3) << 4)); }
                else if (comp == 1) { byte = 24576 + h * 4096 + m * 64 + ((2 * d) ^ (((m >> 1) & 3) << 4)); }
                else { byte = 49152 + h * 4096 + d * 128 + ((2 * m) ^ ((d & 7) << 4)); }
                *(u16*)(lds + byte) = f2b(v);
            }
        }
    }
    __syncthreads();

    // ---- phase 2 setup: wave = (token block tb, head group hg)
    const int tb = w & 3, hg = w >> 2;
    const int t = 16 * tb + lq;            // this lane's token (softmax row)
    bf16x8 qreg[3];
    #pragma unroll
    for (int hh = 0; hh < 3; hh++) {
        int h = hg * 3 + hh;
        int m = 16 * tb + lq;
        qreg[hh] = *(const bf16x8*)(lds + h * 4096 + m * 64 + ((16 * g) ^ (((m >> 1) & 3) << 4)));
    }
    // rel_bias + shift masks + key-pad mask, head-independent: 16 regs
    const bool lastR = (wy == 7), lastC = (wx == 7);
    float bias[4][4];
    #pragma unroll
    for (int mi = 0; mi < 4; mi++)
        #pragma unroll
        for (int r = 0; r < 4; r++) {
            int key = 16 * mi + 4 * g + r;
            float bv;
            if (t < Mn) {
                if (key < Mn) {
                    bv = rel_bias[t * 49 + key];
                    if (lastR && ((t >= 28) != (key >= 28))) bv += NEGV;
                    if (lastC && ((t % 7 >= 4) != (key % 7 >= 4))) bv += NEGV;
                } else bv = NEGV;          // pad keys: exp -> 0
            } else bv = 0.f;               // pad tokens: keep finite
            bias[mi][r] = bv;
        }
    // output bases for this lane's 4 token rows (tokens 16tb+4g+r)
    size_t obase[4]; bool oval[4];
    #pragma unroll
    for (int r = 0; r < 4; r++) {
        int tok = 16 * tb + 4 * g + r;
        oval[r] = tok < Mn;
        int tk = oval[r] ? tok : 0;
        int rr = tk / 7, cc = tk - 7 * rr;
        int oi = (wy * 7 + rr + SH) % HWn;
        int oj = (wx * 7 + cc + SH) % HWn;
        obase[r] = ((size_t)((b * HWn + oi) * HWn + oj)) * En;
    }
    __syncthreads();                       // Q in regs; PL may overlay QS

    // ---- per-head attention (no barriers: PL region is wave-private)
    #pragma unroll
    for (int hh = 0; hh < 3; hh++) {
        int h = hg * 3 + hh;
        // S^T = K . Q^T  (rows=keys, cols=tokens)
        f32x4 st[4];
        #pragma unroll
        for (int mi = 0; mi < 4; mi++) {
            int key = 16 * mi + lq;
            bf16x8 kf = *(const bf16x8*)(lds + 24576 + h * 4096 + key * 64 + ((16 * g) ^ (((key >> 1) & 3) << 4)));
            st[mi] = MFMA(kf, qreg[hh], zero4);
        }
        float mx = -3.4e38f;
        #pragma unroll
        for (int mi = 0; mi < 4; mi++)
            #pragma unroll
            for (int r = 0; r < 4; r++) {
                st[mi][r] += bias[mi][r];
                mx = fmaxf(mx, st[mi][r]);
            }
        mx = fmaxf(mx, __shfl_xor(mx, 16));
        mx = fmaxf(mx, __shfl_xor(mx, 32));
        float sum = 0.f;
        #pragma unroll
        for (int mi = 0; mi < 4; mi++)
            #pragma unroll
            for (int r = 0; r < 4; r++) {
                float e = __expf(st[mi][r] - mx);
                st[mi][r] = e; sum += e;
            }
        sum += __shfl_xor(sum, 16);
        sum += __shfl_xor(sum, 32);
        float inv = 1.f / sum;
        // P -> LDS (wave-private region, swizzled rows of 128B)
        #pragma unroll
        for (int mi = 0; mi < 4; mi++)
            #pragma unroll
            for (int r = 0; r < 4; r++) {
                int key = 16 * mi + 4 * g + r;
                *(u16*)(lds + w * 2048 + lq * 128 + ((2 * key) ^ ((lq & 7) << 4))) = f2b(st[mi][r] * inv);
            }
        // O = P . V   (K = 64 keys = 2 k-tiles of 32)
        f32x4 o0 = zero4, o1 = zero4;
        #pragma unroll
        for (int kf2 = 0; kf2 < 2; kf2++) {
            bf16x8 pf = *(const bf16x8*)(lds + w * 2048 + lq * 128 + ((64 * kf2 + 16 * g) ^ ((lq & 7) << 4)));
            int d0 = lq, d1 = 16 + lq;
            bf16x8 v0 = *(const bf16x8*)(lds + 49152 + h * 4096 + d0 * 128 + ((64 * kf2 + 16 * g) ^ ((d0 & 7) << 4)));
            bf16x8 v1 = *(const bf16x8*)(lds + 49152 + h * 4096 + d1 * 128 + ((64 * kf2 + 16 * g) ^ ((d1 & 7) << 4)));
            o0 = MFMA(pf, v0, o0);
            o1 = MFMA(pf, v1, o1);
        }
        #pragma unroll
        for (int r = 0; r < 4; r++) {
            if (oval[r]) {
                attn_buf[obase[r] + h * 32 + lq]      = o0[r];
                attn_buf[obase[r] + h * 32 + 16 + lq] = o1[r];
            }
        }
    }
}

// ---------------------------------------------------------------------------
// Kernel B: output projection GEMM [100352,192] @ [192,192] + bias (fp32,
// unchanged; in-place safe). ~110 us — next round's target.
// ---------------------------------------------------------------------------
__global__ __launch_bounds__(256) void swin_proj(
    const float* attn_buf, const float* __restrict__ w_out,
    const float* __restrict__ b_out, float* out)
{
    __shared__ float Ts[64][196];
    const int tid = threadIdx.x;
    const size_t tok0 = (size_t)blockIdx.x * 64;

    for (int t = tid; t < 64 * 48; t += 256) {
        int m = t / 48, q = t % 48;
        const float4* src = (const float4*)(attn_buf + (tok0 + m) * En);
        *((float4*)&Ts[m][q * 4]) = src[q];
    }
    __syncthreads();

    const int tm = tid >> 5, tc = tid & 31;
    float acc[8][6];
    #pragma unroll
    for (int j = 0; j < 6; j++) {
        float bj = b_out[tc + 32 * j];
        #pragma unroll
        for (int i = 0; i < 8; i++) acc[i][j] = bj;
    }
    for (int kk = 0; kk < En; kk += 4) {
        float4 xr[8];
        #pragma unroll
        for (int i = 0; i < 8; i++) xr[i] = *((const float4*)&Ts[tm + 8 * i][kk]);
        float wv[4][6];
        #pragma unroll
        for (int q = 0; q < 4; q++) {
            const float* w0 = w_out + (size_t)(kk + q) * En + tc;
            #pragma unroll
            for (int j = 0; j < 6; j++) wv[q][j] = w0[32 * j];
        }
        #pragma unroll
        for (int i = 0; i < 8; i++) {
            const float xv[4] = {xr[i].x, xr[i].y, xr[i].z, xr[i].w};
            #pragma unroll
            for (int q = 0; q < 4; q++)
                #pragma unroll
                for (int j = 0; j < 6; j++)
                    acc[i][j] += xv[q] * wv[q][j];
        }
    }
    #pragma unroll
    for (int i = 0; i < 8; i++) {
        float* dst = out + (tok0 + tm + 8 * i) * En + tc;
        #pragma unroll
        for (int j = 0; j < 6; j++) dst[32 * j] = acc[i][j];
    }
}

extern "C" void kernel_launch(void* const* d_in, const int* in_sizes, int n_in,
                              void* d_out, int out_size, void* d_ws, size_t ws_size,
                              hipStream_t stream) {
    const float* x        = (const float*)d_in[0];
    const float* w_qkv    = (const float*)d_in[1];
    const float* b_qkv    = (const float*)d_in[2];
    const float* w_out    = (const float*)d_in[3];
    const float* b_out    = (const float*)d_in[4];
    const float* rel_bias = (const float*)d_in[5];
    float* out = (float*)d_out;

    const size_t WT_BYTES   = 576 * 192 * 2;               // 221184 (256-aligned)
    const size_t ATTN_BYTES = (size_t)Bn * Ln * En * 4;    // ~77 MB
    char* ws = (char*)d_ws;

    u16* wt = nullptr;
    float* attn_buf;
    bool use_wt;
    if (ws_size >= WT_BYTES + ATTN_BYTES) {
        wt = (u16*)ws; use_wt = true;
        attn_buf = (float*)(ws + WT_BYTES);
    } else if (ws_size >= WT_BYTES) {
        wt = (u16*)ws; use_wt = true;
        attn_buf = out;                    // kernel B is in-place safe
    } else {
        use_wt = false;
        attn_buf = out;
    }

    if (use_wt) {
        prep_wt<<<(576 * 192 + 255) / 256, 256, 0, stream>>>(w_qkv, wt);
        swin_attn_mfma<true><<<2048, 512, 0, stream>>>(x, wt, w_qkv, b_qkv, rel_bias, attn_buf);
    } else {
        swin_attn_mfma<false><<<2048, 512, 0, stream>>>(x, wt, w_qkv, b_qkv, rel_bias, attn_buf);
    }
    swin_proj<<<(Bn * Ln) / 64, 256, 0, stream>>>(attn_buf, w_out, b_out, out);
}

// Round 6
// 285.759 us; speedup vs baseline: 3.5925x; 1.2410x over previous
//
#include <hip/hip_runtime.h>
#include <math.h>

typedef __bf16 bf16x8 __attribute__((ext_vector_type(8)));
typedef float f32x4 __attribute__((ext_vector_type(4)));
typedef unsigned short u16;

constexpr int Bn  = 32;
constexpr int HWn = 56;
constexpr int En  = 192;
constexpr int SH  = 3;
constexpr int NWn = 8;
constexpr int Ln  = HWn * HWn;
constexpr int Mn  = 49;
#define NEGV (-1e9f)

#define MFMA(a, b, c) __builtin_amdgcn_mfma_f32_16x16x32_bf16((a), (b), (c), 0, 0, 0)

__device__ __forceinline__ u16 f2b(float f) {
    unsigned u = __float_as_uint(f);
    return (u16)((u + 0x7fffu + ((u >> 16) & 1u)) >> 16);
}

// row-swizzle for 384B-stride LDS tiles: spreads 8 consecutive rows across
// eight 16B slots (bits 4,5,6 of the byte offset)
__device__ __forceinline__ int xm384(int row) {
    return ((row & 3) << 4) | (((row >> 2) & 1) << 6);
}

// ---------------------------------------------------------------------------
// Prep: W_qkv [192][576] fp32 -> wt bf16 [c'][k], c' = comp*192 + e
//       (de-interleave: source col = e*3+comp);
//       W_out [192][192] fp32 -> wt2 bf16 transposed [c][k] (if do2)
// ---------------------------------------------------------------------------
__global__ __launch_bounds__(256) void prep_w(const float* __restrict__ wq,
                                              const float* __restrict__ wo,
                                              u16* __restrict__ wt,
                                              u16* __restrict__ wt2, int do2) {
    int i = blockIdx.x * 256 + threadIdx.x;
    if (i < 576 * 192) {
        int cp = i / 192, k = i - cp * 192;
        int comp = cp / 192, e = cp - comp * 192;
        wt[i] = f2b(wq[k * 576 + e * 3 + comp]);
    } else if (do2) {
        int i2 = i - 576 * 192;
        if (i2 < 192 * 192) {
            int c = i2 / 192, k = i2 - c * 192;
            wt2[i2] = f2b(wo[k * 192 + c]);
        }
    }
}

// ---------------------------------------------------------------------------
// Kernel A (MFMA): fused QKV projection + shifted-window attention.
// One block per window: grid 2048, 512 threads (8 waves). Unchanged from R5
// except the epilogue optionally stores bf16 (BF16OUT) to halve write traffic.
// ---------------------------------------------------------------------------
template<bool USE_WT, bool BF16OUT>
__global__ __launch_bounds__(512, 2) void swin_attn_mfma(
    const float* __restrict__ x, const u16* __restrict__ wt,
    const float* __restrict__ wq_f32, const float* __restrict__ b_qkv,
    const float* __restrict__ rel_bias, void* __restrict__ attn_outv)
{
    __shared__ char lds[73728] __attribute__((aligned(128)));

    const int tid  = threadIdx.x;
    const int w    = tid >> 6;
    const int lane = tid & 63;
    const int lq   = lane & 15;
    const int g    = lane >> 4;

    const int blk = blockIdx.x;
    const int wx = blk & 7, wy = (blk >> 3) & 7, b = blk >> 6;

    // ---- phase 0: X window -> XS (bf16, swizzled); pad rows 49..63 zeroed
    for (int j = tid; j < 64 * 48; j += 512) {
        int m = j / 48, q = j - 48 * m;
        u16 v[4];
        if (m < Mn) {
            int rr = m / 7, cc = m - 7 * rr;
            int oi = (wy * 7 + rr + SH) % HWn;
            int oj = (wx * 7 + cc + SH) % HWn;
            const float4 f = *(const float4*)(x + ((size_t)((b * HWn + oi) * HWn + oj)) * En + 4 * q);
            v[0] = f2b(f.x); v[1] = f2b(f.y); v[2] = f2b(f.z); v[3] = f2b(f.w);
        } else { v[0] = v[1] = v[2] = v[3] = 0; }
        *(ushort4*)(lds + m * 384 + ((8 * q) ^ xm384(m))) = *(ushort4*)v;
    }

    // ---- phase 1: QKV = X @ W  (M=64, N=576, K=192; 6 k-tiles of 32)
    f32x4 acc[4][5];
    const f32x4 zero4 = {0.f, 0.f, 0.f, 0.f};
    #pragma unroll
    for (int mf = 0; mf < 4; mf++)
        #pragma unroll
        for (int j = 0; j < 5; j++) acc[mf][j] = zero4;

    bf16x8 wreg[5];
    auto stage = [&](int kt) {
        #pragma unroll
        for (int i2 = 0; i2 < 5; i2++) {
            int jj = tid + 512 * i2;
            if (jj < 2304) {
                int c = jj >> 2, q = jj & 3;
                if (USE_WT) {
                    wreg[i2] = *(const bf16x8*)(wt + c * 192 + kt * 32 + q * 8);
                } else {
                    int comp = c / 192, e = c - comp * 192;
                    int col = e * 3 + comp;
                    union { bf16x8 v; u16 a[8]; } t;
                    #pragma unroll
                    for (int p = 0; p < 8; p++)
                        t.a[p] = f2b(wq_f32[(size_t)(kt * 32 + q * 8 + p) * 576 + col]);
                    wreg[i2] = t.v;
                }
            }
        }
    };

    stage(0);
    __syncthreads();                       // XS ready
    for (int kt = 0; kt < 6; kt++) {
        #pragma unroll
        for (int i2 = 0; i2 < 5; i2++) {   // regs -> WT tile (stride-80 rows)
            int jj = tid + 512 * i2;
            if (jj < 2304) {
                int c = jj >> 2, q = jj & 3;
                *(bf16x8*)(lds + 24576 + c * 80 + 16 * q) = wreg[i2];
            }
        }
        __syncthreads();                   // WT tile ready
        if (kt < 5) stage(kt + 1);         // prefetch next (hides under MFMA)

        bf16x8 af[4];
        #pragma unroll
        for (int mf = 0; mf < 4; mf++) {
            int m = 16 * mf + lq;
            af[mf] = *(const bf16x8*)(lds + m * 384 + ((64 * kt + 16 * g) ^ xm384(m)));
        }
        #pragma unroll
        for (int j = 0; j < 5; j++) {
            int nf = w + 8 * j;
            if (nf < 36) {
                int c = 16 * nf + lq;
                bf16x8 bfr = *(const bf16x8*)(lds + 24576 + c * 80 + 16 * g);
                #pragma unroll
                for (int mf = 0; mf < 4; mf++)
                    acc[mf][j] = MFMA(af[mf], bfr, acc[mf][j]);
            }
        }
        __syncthreads();                   // done reading WT before next write
    }

    // ---- scatter C frags (+bias, Q scale) -> QS/KS/VT (bf16, swizzled)
    const float qscale = 0.17677669529663687f;  // 1/sqrt(32)
    #pragma unroll
    for (int j = 0; j < 5; j++) {
        int nf = w + 8 * j;
        if (nf >= 36) continue;
        int comp = nf / 12;
        int e = (nf - comp * 12) * 16 + lq;
        float bcol = b_qkv[e * 3 + comp];
        int h = e >> 5, d = e & 31;
        #pragma unroll
        for (int mf = 0; mf < 4; mf++) {
            #pragma unroll
            for (int r = 0; r < 4; r++) {
                int m = 16 * mf + 4 * g + r;
                float v = acc[mf][j][r] + bcol;
                int byte;
                if (comp == 0) { v *= qscale; byte = h * 4096 + m * 64 + ((2 * d) ^ (((m >> 1) & 3) << 4)); }
                else if (comp == 1) { byte = 24576 + h * 4096 + m * 64 + ((2 * d) ^ (((m >> 1) & 3) << 4)); }
                else { byte = 49152 + h * 4096 + d * 128 + ((2 * m) ^ ((d & 7) << 4)); }
                *(u16*)(lds + byte) = f2b(v);
            }
        }
    }
    __syncthreads();

    // ---- phase 2 setup: wave = (token block tb, head group hg)
    const int tb = w & 3, hg = w >> 2;
    const int t = 16 * tb + lq;            // this lane's token (softmax row)
    bf16x8 qreg[3];
    #pragma unroll
    for (int hh = 0; hh < 3; hh++) {
        int h = hg * 3 + hh;
        int m = 16 * tb + lq;
        qreg[hh] = *(const bf16x8*)(lds + h * 4096 + m * 64 + ((16 * g) ^ (((m >> 1) & 3) << 4)));
    }
    const bool lastR = (wy == 7), lastC = (wx == 7);
    float bias[4][4];
    #pragma unroll
    for (int mi = 0; mi < 4; mi++)
        #pragma unroll
        for (int r = 0; r < 4; r++) {
            int key = 16 * mi + 4 * g + r;
            float bv;
            if (t < Mn) {
                if (key < Mn) {
                    bv = rel_bias[t * 49 + key];
                    if (lastR && ((t >= 28) != (key >= 28))) bv += NEGV;
                    if (lastC && ((t % 7 >= 4) != (key % 7 >= 4))) bv += NEGV;
                } else bv = NEGV;          // pad keys: exp -> 0
            } else bv = 0.f;               // pad tokens: keep finite
            bias[mi][r] = bv;
        }
    size_t obase[4]; bool oval[4];
    #pragma unroll
    for (int r = 0; r < 4; r++) {
        int tok = 16 * tb + 4 * g + r;
        oval[r] = tok < Mn;
        int tk = oval[r] ? tok : 0;
        int rr = tk / 7, cc = tk - 7 * rr;
        int oi = (wy * 7 + rr + SH) % HWn;
        int oj = (wx * 7 + cc + SH) % HWn;
        obase[r] = ((size_t)((b * HWn + oi) * HWn + oj)) * En;
    }
    __syncthreads();                       // Q in regs; PL may overlay QS

    // ---- per-head attention (no barriers: PL region is wave-private)
    #pragma unroll
    for (int hh = 0; hh < 3; hh++) {
        int h = hg * 3 + hh;
        f32x4 st[4];
        #pragma unroll
        for (int mi = 0; mi < 4; mi++) {
            int key = 16 * mi + lq;
            bf16x8 kf = *(const bf16x8*)(lds + 24576 + h * 4096 + key * 64 + ((16 * g) ^ (((key >> 1) & 3) << 4)));
            st[mi] = MFMA(kf, qreg[hh], zero4);
        }
        float mx = -3.4e38f;
        #pragma unroll
        for (int mi = 0; mi < 4; mi++)
            #pragma unroll
            for (int r = 0; r < 4; r++) {
                st[mi][r] += bias[mi][r];
                mx = fmaxf(mx, st[mi][r]);
            }
        mx = fmaxf(mx, __shfl_xor(mx, 16));
        mx = fmaxf(mx, __shfl_xor(mx, 32));
        float sum = 0.f;
        #pragma unroll
        for (int mi = 0; mi < 4; mi++)
            #pragma unroll
            for (int r = 0; r < 4; r++) {
                float e = __expf(st[mi][r] - mx);
                st[mi][r] = e; sum += e;
            }
        sum += __shfl_xor(sum, 16);
        sum += __shfl_xor(sum, 32);
        float inv = 1.f / sum;
        #pragma unroll
        for (int mi = 0; mi < 4; mi++)
            #pragma unroll
            for (int r = 0; r < 4; r++) {
                int key = 16 * mi + 4 * g + r;
                *(u16*)(lds + w * 2048 + lq * 128 + ((2 * key) ^ ((lq & 7) << 4))) = f2b(st[mi][r] * inv);
            }
        // O = P . V   (K = 64 keys = 2 k-tiles of 32)
        f32x4 o0 = zero4, o1 = zero4;
        #pragma unroll
        for (int kf2 = 0; kf2 < 2; kf2++) {
            bf16x8 pf = *(const bf16x8*)(lds + w * 2048 + lq * 128 + ((64 * kf2 + 16 * g) ^ ((lq & 7) << 4)));
            int d0 = lq, d1 = 16 + lq;
            bf16x8 v0 = *(const bf16x8*)(lds + 49152 + h * 4096 + d0 * 128 + ((64 * kf2 + 16 * g) ^ ((d0 & 7) << 4)));
            bf16x8 v1 = *(const bf16x8*)(lds + 49152 + h * 4096 + d1 * 128 + ((64 * kf2 + 16 * g) ^ ((d1 & 7) << 4)));
            o0 = MFMA(pf, v0, o0);
            o1 = MFMA(pf, v1, o1);
        }
        #pragma unroll
        for (int r = 0; r < 4; r++) {
            if (oval[r]) {
                if (BF16OUT) {
                    u16* ab = (u16*)attn_outv;
                    ab[obase[r] + h * 32 + lq]      = f2b(o0[r]);
                    ab[obase[r] + h * 32 + 16 + lq] = f2b(o1[r]);
                } else {
                    float* ab = (float*)attn_outv;
                    ab[obase[r] + h * 32 + lq]      = o0[r];
                    ab[obase[r] + h * 32 + 16 + lq] = o1[r];
                }
            }
        }
    }
}

// ---------------------------------------------------------------------------
// Kernel B (MFMA): out = attn @ W_out + b_out.  M=100352, N=192, K=192.
// 512 threads (8 waves), M_BLK=128 (1 m-frag/wave), full N,K in LDS, ONE
// barrier, 72 MFMA/wave. grid 784. LDS: AS 128x384B @0 | BS 192x384B @49152
// (120 KB, 1 block/CU). In-place safe for fp32 input (reads own rows only).
// ---------------------------------------------------------------------------
template<bool BF16IN, bool USE_WT2>
__global__ __launch_bounds__(512) void swin_proj_mfma(
    const void* __restrict__ attn_in, const u16* __restrict__ wt2,
    const float* __restrict__ w_out, const float* __restrict__ b_out,
    float* __restrict__ out)
{
    __shared__ char lds[122880] __attribute__((aligned(128)));
    const int tid = threadIdx.x;
    const size_t tok0 = (size_t)blockIdx.x * 128;

    // stage B = W_out^T (192 rows of 192 k-values)
    for (int j = tid; j < 192 * 24; j += 512) {
        int c = j / 24, q = j - 24 * c;
        bf16x8 v;
        if (USE_WT2) {
            v = *(const bf16x8*)(wt2 + c * 192 + 8 * q);
        } else {
            union { bf16x8 v; u16 a[8]; } t;
            #pragma unroll
            for (int p = 0; p < 8; p++)
                t.a[p] = f2b(w_out[(8 * q + p) * 192 + c]);
            v = t.v;
        }
        *(bf16x8*)(lds + 49152 + c * 384 + ((16 * q) ^ xm384(c))) = v;
    }
    // stage A tile (128 tokens x 192)
    for (int j = tid; j < 128 * 24; j += 512) {
        int m = j / 24, q = j - 24 * m;
        bf16x8 v;
        if (BF16IN) {
            v = *(const bf16x8*)((const u16*)attn_in + (tok0 + m) * En + 8 * q);
        } else {
            const float* src = (const float*)attn_in + (tok0 + m) * En + 8 * q;
            float4 f0 = *(const float4*)src, f1 = *(const float4*)(src + 4);
            union { bf16x8 v; u16 a[8]; } t;
            t.a[0] = f2b(f0.x); t.a[1] = f2b(f0.y); t.a[2] = f2b(f0.z); t.a[3] = f2b(f0.w);
            t.a[4] = f2b(f1.x); t.a[5] = f2b(f1.y); t.a[6] = f2b(f1.z); t.a[7] = f2b(f1.w);
            v = t.v;
        }
        *(bf16x8*)(lds + m * 384 + ((16 * q) ^ xm384(m))) = v;
    }
    __syncthreads();

    const int w  = tid >> 6;
    const int lq = tid & 15;
    const int g  = (tid & 63) >> 4;

    f32x4 acc[12];
    #pragma unroll
    for (int nf = 0; nf < 12; nf++) {
        float bj = b_out[16 * nf + lq];
        acc[nf] = (f32x4){bj, bj, bj, bj};
    }
    #pragma unroll
    for (int kt = 0; kt < 6; kt++) {
        int m = 16 * w + lq;
        bf16x8 af = *(const bf16x8*)(lds + m * 384 + ((64 * kt + 16 * g) ^ xm384(m)));
        #pragma unroll
        for (int nf = 0; nf < 12; nf++) {
            int c = 16 * nf + lq;
            bf16x8 bf = *(const bf16x8*)(lds + 49152 + c * 384 + ((64 * kt + 16 * g) ^ xm384(c)));
            acc[nf] = MFMA(af, bf, acc[nf]);
        }
    }
    #pragma unroll
    for (int nf = 0; nf < 12; nf++)
        #pragma unroll
        for (int r = 0; r < 4; r++)
            out[(tok0 + 16 * w + 4 * g + r) * En + 16 * nf + lq] = acc[nf][r];
}

extern "C" void kernel_launch(void* const* d_in, const int* in_sizes, int n_in,
                              void* d_out, int out_size, void* d_ws, size_t ws_size,
                              hipStream_t stream) {
    const float* x        = (const float*)d_in[0];
    const float* w_qkv    = (const float*)d_in[1];
    const float* b_qkv    = (const float*)d_in[2];
    const float* w_out    = (const float*)d_in[3];
    const float* b_out    = (const float*)d_in[4];
    const float* rel_bias = (const float*)d_in[5];
    float* out = (float*)d_out;

    const size_t WT  = 576 * 192 * 2;                 // 221184
    const size_t WT2 = 192 * 192 * 2;                 // 73728
    const size_t A2  = (size_t)Bn * Ln * En * 2;      // bf16 attn: ~38.5 MB
    char* ws = (char*)d_ws;

    const int GRID_A = Bn * NWn * NWn;                // 2048 windows
    const int GRID_B = (Bn * Ln) / 128;               // 784

    if (ws_size >= WT + WT2 + A2) {
        u16* wt  = (u16*)ws;
        u16* wt2 = (u16*)(ws + WT);
        u16* attn2 = (u16*)(ws + WT + WT2);
        prep_w<<<576, 256, 0, stream>>>(w_qkv, w_out, wt, wt2, 1);
        swin_attn_mfma<true, true><<<GRID_A, 512, 0, stream>>>(x, wt, w_qkv, b_qkv, rel_bias, attn2);
        swin_proj_mfma<true, true><<<GRID_B, 512, 0, stream>>>(attn2, wt2, w_out, b_out, out);
    } else if (ws_size >= WT + WT2) {
        u16* wt  = (u16*)ws;
        u16* wt2 = (u16*)(ws + WT);
        prep_w<<<576, 256, 0, stream>>>(w_qkv, w_out, wt, wt2, 1);
        swin_attn_mfma<true, false><<<GRID_A, 512, 0, stream>>>(x, wt, w_qkv, b_qkv, rel_bias, out);
        swin_proj_mfma<false, true><<<GRID_B, 512, 0, stream>>>(out, wt2, w_out, b_out, out);
    } else if (ws_size >= WT) {
        u16* wt = (u16*)ws;
        prep_w<<<432, 256, 0, stream>>>(w_qkv, w_out, wt, nullptr, 0);
        swin_attn_mfma<true, false><<<GRID_A, 512, 0, stream>>>(x, wt, w_qkv, b_qkv, rel_bias, out);
        swin_proj_mfma<false, false><<<GRID_B, 512, 0, stream>>>(out, nullptr, w_out, b_out, out);
    } else {
        swin_attn_mfma<false, false><<<GRID_A, 512, 0, stream>>>(x, nullptr, w_qkv, b_qkv, rel_bias, out);
        swin_proj_mfma<false, false><<<GRID_B, 512, 0, stream>>>(out, nullptr, w_out, b_out, out);
    }
}

// Round 8
// 283.344 us; speedup vs baseline: 3.6231x; 1.0085x over previous
//
#include <hip/hip_runtime.h>
#include <math.h>

typedef __bf16 bf16x8 __attribute__((ext_vector_type(8)));
typedef float f32x4 __attribute__((ext_vector_type(4)));
typedef unsigned short u16;

constexpr int Bn  = 32;
constexpr int HWn = 56;
constexpr int En  = 192;
constexpr int SH  = 3;
constexpr int NWn = 8;
constexpr int Ln  = HWn * HWn;
constexpr int Mn  = 49;
#define NEGV (-1e9f)

#define MFMA(a, b, c) __builtin_amdgcn_mfma_f32_16x16x32_bf16((a), (b), (c), 0, 0, 0)

__device__ __forceinline__ u16 f2b(float f) {
    unsigned u = __float_as_uint(f);
    return (u16)((u + 0x7fffu + ((u >> 16) & 1u)) >> 16);
}

// row-swizzle for 384B-stride LDS tiles (bits 4..6 of byte offset)
__device__ __forceinline__ int xm384(int row) {
    return ((row & 3) << 4) | (((row >> 2) & 1) << 6);
}

// ---------------------------------------------------------------------------
// Prep: W_qkv [192][576] fp32 -> wt bf16 [c'][k], c' = comp*192 + e
//       (de-interleave: source col = e*3+comp);
//       W_out [192][192] fp32 -> wt2 bf16 transposed [c][k] (if do2)
// ---------------------------------------------------------------------------
__global__ __launch_bounds__(256) void prep_w(const float* __restrict__ wq,
                                              const float* __restrict__ wo,
                                              u16* __restrict__ wt,
                                              u16* __restrict__ wt2, int do2) {
    int i = blockIdx.x * 256 + threadIdx.x;
    if (i < 576 * 192) {
        int cp = i / 192, k = i - cp * 192;
        int comp = cp / 192, e = cp - comp * 192;
        wt[i] = f2b(wq[k * 576 + e * 3 + comp]);
    } else if (do2) {
        int i2 = i - 576 * 192;
        if (i2 < 192 * 192) {
            int c = i2 / 192, k = i2 - c * 192;
            wt2[i2] = f2b(wo[k * 192 + c]);
        }
    }
}

// ---------------------------------------------------------------------------
// Fully-fused kernel: X -> QKV -> windowed attention -> output projection.
// One block per window: grid 2048, 512 threads (8 waves), LDS 72 KB (2/CU).
// LDS layout (bytes):
//   phase1: XS [64r][384B] @0 | WT [576r][80B pad] @24576 (ends 70656)
//   phase2: QS [6][64][64B] @0 | KS @24576 | VT [6][32][128B] @49152
//   phase2b: PL [8w][16][128B] @0 (overlays QS after Q->regs)
//   phase3: OS [64r][384B] @24576 (overlays dead KS), proj reads it back.
// Proj phase mirrors R6's verified swin_proj_mfma operand mapping.
// ---------------------------------------------------------------------------
template<bool USE_WT, bool USE_WT2>
__global__ __launch_bounds__(512, 2) void swin_fused(
    const float* __restrict__ x, const u16* __restrict__ wt,
    const u16* __restrict__ wt2,
    const float* __restrict__ wq_f32, const float* __restrict__ b_qkv,
    const float* __restrict__ w_out, const float* __restrict__ b_out,
    const float* __restrict__ rel_bias, float* __restrict__ out)
{
    __shared__ char lds[73728] __attribute__((aligned(128)));

    const int tid  = threadIdx.x;
    const int w    = tid >> 6;
    const int lane = tid & 63;
    const int lq   = lane & 15;
    const int g    = lane >> 4;

    const int blk = blockIdx.x;
    const int wx = blk & 7, wy = (blk >> 3) & 7, b = blk >> 6;

    // ---- phase 0: X window -> XS (bf16, swizzled); pad rows 49..63 zeroed
    for (int j = tid; j < 64 * 48; j += 512) {
        int m = j / 48, q = j - 48 * m;
        u16 v[4];
        if (m < Mn) {
            int rr = m / 7, cc = m - 7 * rr;
            int oi = (wy * 7 + rr + SH) % HWn;
            int oj = (wx * 7 + cc + SH) % HWn;
            const float4 f = *(const float4*)(x + ((size_t)((b * HWn + oi) * HWn + oj)) * En + 4 * q);
            v[0] = f2b(f.x); v[1] = f2b(f.y); v[2] = f2b(f.z); v[3] = f2b(f.w);
        } else { v[0] = v[1] = v[2] = v[3] = 0; }
        *(ushort4*)(lds + m * 384 + ((8 * q) ^ xm384(m))) = *(ushort4*)v;
    }

    // ---- phase 1: QKV = X @ W  (M=64, N=576, K=192; 6 k-tiles of 32)
    f32x4 acc[4][5];
    const f32x4 zero4 = {0.f, 0.f, 0.f, 0.f};
    #pragma unroll
    for (int mf = 0; mf < 4; mf++)
        #pragma unroll
        for (int j = 0; j < 5; j++) acc[mf][j] = zero4;

    bf16x8 wreg[5];
    auto stage = [&](int kt) {
        #pragma unroll
        for (int i2 = 0; i2 < 5; i2++) {
            int jj = tid + 512 * i2;
            if (jj < 2304) {
                int c = jj >> 2, q = jj & 3;
                if (USE_WT) {
                    wreg[i2] = *(const bf16x8*)(wt + c * 192 + kt * 32 + q * 8);
                } else {
                    int comp = c / 192, e = c - comp * 192;
                    int col = e * 3 + comp;
                    union { bf16x8 v; u16 a[8]; } t;
                    #pragma unroll
                    for (int p = 0; p < 8; p++)
                        t.a[p] = f2b(wq_f32[(size_t)(kt * 32 + q * 8 + p) * 576 + col]);
                    wreg[i2] = t.v;
                }
            }
        }
    };

    stage(0);
    __syncthreads();                       // XS ready
    for (int kt = 0; kt < 6; kt++) {
        #pragma unroll
        for (int i2 = 0; i2 < 5; i2++) {   // regs -> WT tile (stride-80 rows)
            int jj = tid + 512 * i2;
            if (jj < 2304) {
                int c = jj >> 2, q = jj & 3;
                *(bf16x8*)(lds + 24576 + c * 80 + 16 * q) = wreg[i2];
            }
        }
        __syncthreads();                   // WT tile ready
        if (kt < 5) stage(kt + 1);         // prefetch next (hides under MFMA)

        bf16x8 af[4];
        #pragma unroll
        for (int mf = 0; mf < 4; mf++) {
            int m = 16 * mf + lq;
            af[mf] = *(const bf16x8*)(lds + m * 384 + ((64 * kt + 16 * g) ^ xm384(m)));
        }
        #pragma unroll
        for (int j = 0; j < 5; j++) {
            int nf = w + 8 * j;
            if (nf < 36) {
                int c = 16 * nf + lq;
                bf16x8 bfr = *(const bf16x8*)(lds + 24576 + c * 80 + 16 * g);
                #pragma unroll
                for (int mf = 0; mf < 4; mf++)
                    acc[mf][j] = MFMA(af[mf], bfr, acc[mf][j]);
            }
        }
        __syncthreads();                   // done reading WT before next write
    }

    // ---- scatter C frags (+bias, Q scale) -> QS/KS/VT (bf16, swizzled)
    const float qscale = 0.17677669529663687f;  // 1/sqrt(32)
    #pragma unroll
    for (int j = 0; j < 5; j++) {
        int nf = w + 8 * j;
        if (nf >= 36) continue;
        int comp = nf / 12;
        int e = (nf - comp * 12) * 16 + lq;
        float bcol = b_qkv[e * 3 + comp];
        int h = e >> 5, d = e & 31;
        #pragma unroll
        for (int mf = 0; mf < 4; mf++) {
            #pragma unroll
            for (int r = 0; r < 4; r++) {
                int m = 16 * mf + 4 * g + r;
                float v = acc[mf][j][r] + bcol;
                int byte;
                if (comp == 0) { v *= qscale; byte = h * 4096 + m * 64 + ((2 * d) ^ (((m >> 1) & 3) << 4)); }
                else if (comp == 1) { byte = 24576 + h * 4096 + m * 64 + ((2 * d) ^ (((m >> 1) & 3) << 4)); }
                else { byte = 49152 + h * 4096 + d * 128 + ((2 * m) ^ ((d & 7) << 4)); }
                *(u16*)(lds + byte) = f2b(v);
            }
        }
    }
    __syncthreads();

    // ---- phase 2 setup: wave = (token block tb, head group hg)
    const int tb = w & 3, hg = w >> 2;
    const int t = 16 * tb + lq;            // this lane's token (softmax row)
    bf16x8 qreg[3];
    #pragma unroll
    for (int hh = 0; hh < 3; hh++) {
        int h = hg * 3 + hh;
        int m = 16 * tb + lq;
        qreg[hh] = *(const bf16x8*)(lds + h * 4096 + m * 64 + ((16 * g) ^ (((m >> 1) & 3) << 4)));
    }
    const bool lastR = (wy == 7), lastC = (wx == 7);
    float bias[4][4];
    #pragma unroll
    for (int mi = 0; mi < 4; mi++)
        #pragma unroll
        for (int r = 0; r < 4; r++) {
            int key = 16 * mi + 4 * g + r;
            float bv;
            if (t < Mn) {
                if (key < Mn) {
                    bv = rel_bias[t * 49 + key];
                    if (lastR && ((t >= 28) != (key >= 28))) bv += NEGV;
                    if (lastC && ((t % 7 >= 4) != (key % 7 >= 4))) bv += NEGV;
                } else bv = NEGV;          // pad keys: exp -> 0
            } else bv = 0.f;               // pad tokens: keep finite
            bias[mi][r] = bv;
        }
    __syncthreads();                       // Q in regs; PL may overlay QS

    // ---- per-head attention; keep O frags in regs (oacc[3][2])
    f32x4 oacc[3][2];
    #pragma unroll
    for (int hh = 0; hh < 3; hh++) {
        int h = hg * 3 + hh;
        f32x4 st[4];
        #pragma unroll
        for (int mi = 0; mi < 4; mi++) {
            int key = 16 * mi + lq;
            bf16x8 kf = *(const bf16x8*)(lds + 24576 + h * 4096 + key * 64 + ((16 * g) ^ (((key >> 1) & 3) << 4)));
            st[mi] = MFMA(kf, qreg[hh], zero4);
        }
        float mx = -3.4e38f;
        #pragma unroll
        for (int mi = 0; mi < 4; mi++)
            #pragma unroll
            for (int r = 0; r < 4; r++) {
                st[mi][r] += bias[mi][r];
                mx = fmaxf(mx, st[mi][r]);
            }
        mx = fmaxf(mx, __shfl_xor(mx, 16));
        mx = fmaxf(mx, __shfl_xor(mx, 32));
        float sum = 0.f;
        #pragma unroll
        for (int mi = 0; mi < 4; mi++)
            #pragma unroll
            for (int r = 0; r < 4; r++) {
                float e = __expf(st[mi][r] - mx);
                st[mi][r] = e; sum += e;
            }
        sum += __shfl_xor(sum, 16);
        sum += __shfl_xor(sum, 32);
        float inv = 1.f / sum;
        #pragma unroll
        for (int mi = 0; mi < 4; mi++)
            #pragma unroll
            for (int r = 0; r < 4; r++) {
                int key = 16 * mi + 4 * g + r;
                *(u16*)(lds + w * 2048 + lq * 128 + ((2 * key) ^ ((lq & 7) << 4))) = f2b(st[mi][r] * inv);
            }
        // O = P . V   (K = 64 keys = 2 k-tiles of 32)
        f32x4 o0 = zero4, o1 = zero4;
        #pragma unroll
        for (int kf2 = 0; kf2 < 2; kf2++) {
            bf16x8 pf = *(const bf16x8*)(lds + w * 2048 + lq * 128 + ((64 * kf2 + 16 * g) ^ ((lq & 7) << 4)));
            int d0 = lq, d1 = 16 + lq;
            bf16x8 v0 = *(const bf16x8*)(lds + 49152 + h * 4096 + d0 * 128 + ((64 * kf2 + 16 * g) ^ ((d0 & 7) << 4)));
            bf16x8 v1 = *(const bf16x8*)(lds + 49152 + h * 4096 + d1 * 128 + ((64 * kf2 + 16 * g) ^ ((d1 & 7) << 4)));
            o0 = MFMA(pf, v0, o0);
            o1 = MFMA(pf, v1, o1);
        }
        oacc[hh][0] = o0;
        oacc[hh][1] = o1;
    }

    // ---- phase 3: output projection, fused.
    // OS [64 tok][192 ch] bf16 @24576 (overlays KS; all KS reads done above).
    __syncthreads();
    #pragma unroll
    for (int hh = 0; hh < 3; hh++) {
        int h = hg * 3 + hh;
        #pragma unroll
        for (int r = 0; r < 4; r++) {
            int tk = 16 * tb + 4 * g + r;
            int c0 = h * 32 + lq;
            *(u16*)(lds + 24576 + tk * 384 + ((2 * c0) ^ xm384(tk)))        = f2b(oacc[hh][0][r]);
            *(u16*)(lds + 24576 + tk * 384 + ((2 * (c0 + 16)) ^ xm384(tk))) = f2b(oacc[hh][1][r]);
        }
    }
    __syncthreads();

    // proj GEMM: M=64 (4 mf), N=192 (12 nf), K=192 (6 kt); waves 2m x 4n.
    const int wm = w >> 2, wn = w & 3;
    f32x4 pacc[2][3];
    #pragma unroll
    for (int mi = 0; mi < 2; mi++)
        #pragma unroll
        for (int nj = 0; nj < 3; nj++) {
            float bj = b_out[16 * (3 * wn + nj) + lq];
            pacc[mi][nj] = (f32x4){bj, bj, bj, bj};
        }
    #pragma unroll
    for (int kt = 0; kt < 6; kt++) {
        bf16x8 paf[2];
        #pragma unroll
        for (int mi = 0; mi < 2; mi++) {
            int row = 16 * (2 * wm + mi) + lq;
            paf[mi] = *(const bf16x8*)(lds + 24576 + row * 384 + ((64 * kt + 16 * g) ^ xm384(row)));
        }
        #pragma unroll
        for (int nj = 0; nj < 3; nj++) {
            int c = 16 * (3 * wn + nj) + lq;
            bf16x8 pbf;
            if (USE_WT2) {
                pbf = *(const bf16x8*)(wt2 + c * 192 + kt * 32 + 8 * g);
            } else {
                union { bf16x8 v; u16 a[8]; } tt;
                #pragma unroll
                for (int p = 0; p < 8; p++)
                    tt.a[p] = f2b(w_out[(kt * 32 + 8 * g + p) * 192 + c]);
                pbf = tt.v;
            }
            #pragma unroll
            for (int mi = 0; mi < 2; mi++)
                pacc[mi][nj] = MFMA(paf[mi], pbf, pacc[mi][nj]);
        }
    }
    // epilogue: scatter final fp32 rows to un-rolled positions
    #pragma unroll
    for (int mi = 0; mi < 2; mi++)
        #pragma unroll
        for (int r = 0; r < 4; r++) {
            int tok = 16 * (2 * wm + mi) + 4 * g + r;
            if (tok < Mn) {
                int rr = tok / 7, cc = tok - 7 * rr;
                int oi = (wy * 7 + rr + SH) % HWn;
                int oj = (wx * 7 + cc + SH) % HWn;
                float* dst = out + ((size_t)((b * HWn + oi) * HWn + oj)) * En;
                #pragma unroll
                for (int nj = 0; nj < 3; nj++)
                    dst[16 * (3 * wn + nj) + lq] = pacc[mi][nj][r];
            }
        }
}

extern "C" void kernel_launch(void* const* d_in, const int* in_sizes, int n_in,
                              void* d_out, int out_size, void* d_ws, size_t ws_size,
                              hipStream_t stream) {
    const float* x        = (const float*)d_in[0];
    const float* w_qkv    = (const float*)d_in[1];
    const float* b_qkv    = (const float*)d_in[2];
    const float* w_out    = (const float*)d_in[3];
    const float* b_out    = (const float*)d_in[4];
    const float* rel_bias = (const float*)d_in[5];
    float* out = (float*)d_out;

    const size_t WT  = 576 * 192 * 2;                 // 221184
    const size_t WT2 = 192 * 192 * 2;                 // 73728
    char* ws = (char*)d_ws;

    const int GRID_A = Bn * NWn * NWn;                // 2048 windows

    if (ws_size >= WT + WT2) {
        u16* wt  = (u16*)ws;
        u16* wt2 = (u16*)(ws + WT);
        prep_w<<<576, 256, 0, stream>>>(w_qkv, w_out, wt, wt2, 1);
        swin_fused<true, true><<<GRID_A, 512, 0, stream>>>(
            x, wt, wt2, w_qkv, b_qkv, w_out, b_out, rel_bias, out);
    } else if (ws_size >= WT) {
        u16* wt = (u16*)ws;
        prep_w<<<432, 256, 0, stream>>>(w_qkv, w_out, wt, nullptr, 0);
        swin_fused<true, false><<<GRID_A, 512, 0, stream>>>(
            x, wt, nullptr, w_qkv, b_qkv, w_out, b_out, rel_bias, out);
    } else {
        swin_fused<false, false><<<GRID_A, 512, 0, stream>>>(
            x, nullptr, nullptr, w_qkv, b_qkv, w_out, b_out, rel_bias, out);
    }
}